// Round 5
// baseline (482.414 us; speedup 1.0000x reference)
//
#include <hip/hip_runtime.h>
#include <math.h>

#define N_REL  8
#define IN_CH  16
#define HID_CH 32
#define OUT_CH 2
#define BNODES 32                 // nodes per bucket
#define BKEYS  (BNODES * N_REL)   // 256 (dst,rel) keys per bucket

// float -> bf16 round-to-nearest-even
static __device__ __forceinline__ unsigned short f2b(float f) {
    unsigned int u = __float_as_uint(f);
    u = (u + 0x7FFFu + ((u >> 16) & 1u)) >> 16;
    return (unsigned short)u;
}
static __device__ __forceinline__ float b2f(unsigned short s) {
    return __uint_as_float(((unsigned int)s) << 16);
}

// ---------------------------------------------------------------------------
// A: per-bucket edge counts (3125 hot counters, cache-resident)
// ---------------------------------------------------------------------------
__global__ void bucket_count_kernel(const int* __restrict__ dst,
                                    int* __restrict__ bcnt, int E) {
    int e = blockIdx.x * blockDim.x + threadIdx.x;
    if (e < E) atomicAdd(&bcnt[dst[e] >> 5], 1);
}

// ---------------------------------------------------------------------------
// exclusive scan of bcnt[0..nbuck) in place (single wave); bcnt[nbuck] = E
// ---------------------------------------------------------------------------
__global__ void bucket_scan_kernel(int* __restrict__ b, int nbuck) {
    int lane = threadIdx.x & 63;
    int run = 0;
    for (int base = 0; base < nbuck; base += 64) {
        int i = base + lane;
        int val = (i < nbuck) ? b[i] : 0;
        int v = val;
#pragma unroll
        for (int off = 1; off < 64; off <<= 1) {
            int u = __shfl_up(v, off, 64);
            if (lane >= off) v += u;
        }
        if (i < nbuck) b[i] = run + (v - val);
        run += __shfl(v, 63, 64);
    }
    if (lane == 0) b[nbuck] = run;
}

// ---------------------------------------------------------------------------
// B: scatter packed edge records into bucket-contiguous regions.
// bbase[b] is bumped to its segment END (start of b+1) in the process.
// pack: (local_dst<<20) | (rel<<17) | src   (src < 2^17)
// ---------------------------------------------------------------------------
__global__ void bucket_scatter_kernel(const int* __restrict__ src,
                                      const int* __restrict__ dst,
                                      const int* __restrict__ rel,
                                      int* __restrict__ bbase,
                                      int* __restrict__ be, int E) {
    int e = blockIdx.x * blockDim.x + threadIdx.x;
    if (e >= E) return;
    int d = dst[e];
    int slot = atomicAdd(&bbase[d >> 5], 1);
    be[slot] = ((d & 31) << 20) | (rel[e] << 17) | src[e];
}

// ---------------------------------------------------------------------------
// C: per-bucket counting sort -> rel-sorted CSR + per-(node,rel) segment ends.
// One block per bucket; all global writes sequential.
// ---------------------------------------------------------------------------
__global__ __launch_bounds__(256) void bucket_build_kernel(const int* __restrict__ be,
                                                           const int* __restrict__ bends,
                                                           int* __restrict__ ends,
                                                           int* __restrict__ csr, int M) {
    int b  = blockIdx.x;
    int s0 = (b > 0) ? bends[b - 1] : 0;
    int s1 = bends[b];
    int t  = threadIdx.x;

    __shared__ int cnt[BKEYS];
    __shared__ int off[BKEYS];
    __shared__ int fil[BKEYS];
    cnt[t] = 0; fil[t] = 0;
    __syncthreads();

    for (int p = s0 + t; p < s1; p += 256)
        atomicAdd(&cnt[(be[p] >> 17) & 255], 1);
    __syncthreads();

    // block-wide inclusive Hillis-Steele scan over the 256 keys
    int v = cnt[t];
    off[t] = v;
    __syncthreads();
#pragma unroll
    for (int d = 1; d < 256; d <<= 1) {
        int add = (t >= d) ? off[t - d] : 0;
        __syncthreads();
        off[t] += add;
        __syncthreads();
    }

    int gidx = b * BKEYS + t;
    if (gidx < M) ends[gidx] = s0 + off[t];      // global inclusive segment end

    for (int p = s0 + t; p < s1; p += 256) {
        int pk = be[p];
        int k  = (pk >> 17) & 255;
        int slot = s0 + (off[k] - cnt[k]) + atomicAdd(&fil[k], 1);
        csr[slot] = pk & 0x1FFFF;
    }
}

// ---------------------------------------------------------------------------
// xw: xW16[n][r][c] = bf16( x[n] @ W1[r][:,c] )
// ---------------------------------------------------------------------------
#define XW_TILE 64
__global__ __launch_bounds__(256) void xw_kernel(const float* __restrict__ x,
                                                 const float* __restrict__ W1,
                                                 unsigned short* __restrict__ xW16, int N) {
    __shared__ float sx[XW_TILE * IN_CH];   // 4 KB
    int t = threadIdx.x;
    int node0 = blockIdx.x * XW_TILE;

    {
        int i4 = node0 * 4 + t;
        float4 v = make_float4(0.f, 0.f, 0.f, 0.f);
        if (i4 < N * 4) v = ((const float4*)x)[i4];
        ((float4*)sx)[t] = v;
    }
    __syncthreads();

    int r = t >> 5, c = t & 31;
    float w[IN_CH];
#pragma unroll
    for (int f = 0; f < IN_CH; ++f)
        w[f] = W1[(r * IN_CH + f) * HID_CH + c];

    int lim = N - node0; if (lim > XW_TILE) lim = XW_TILE;
    for (int ni = 0; ni < lim; ++ni) {
        const float4* xs = (const float4*)(sx + ni * IN_CH);
        float4 v0 = xs[0], v1 = xs[1], v2 = xs[2], v3 = xs[3];
        float a;
        a  = v0.x * w[0]  + v0.y * w[1]  + v0.z * w[2]  + v0.w * w[3];
        a += v1.x * w[4]  + v1.y * w[5]  + v1.z * w[6]  + v1.w * w[7];
        a += v2.x * w[8]  + v2.y * w[9]  + v2.z * w[10] + v2.w * w[11];
        a += v3.x * w[12] + v3.y * w[13] + v3.z * w[14] + v3.w * w[15];
        xW16[(node0 + ni) * (N_REL * HID_CH) + t] = f2b(a);
    }
}

// ---------------------------------------------------------------------------
// l1 gather: half-wave per node, lane = hidden channel c.
// ---------------------------------------------------------------------------
__global__ __launch_bounds__(256) void l1_gather_kernel(const float* __restrict__ x,
                                                        const int* __restrict__ csr,
                                                        const int* __restrict__ ends,
                                                        const unsigned short* __restrict__ xW16,
                                                        const float* __restrict__ root1,
                                                        const float* __restrict__ b1,
                                                        float* __restrict__ h, int N) {
    int gid  = blockIdx.x * 256 + threadIdx.x;
    int node = gid >> 5;
    int c    = gid & 31;
    if (node >= N) return;

    int4 e0 = ((const int4*)ends)[node * 2];
    int4 e1 = ((const int4*)ends)[node * 2 + 1];
    int end_r[N_REL] = {e0.x, e0.y, e0.z, e0.w, e1.x, e1.y, e1.z, e1.w};

    int prev = (node > 0) ? __ldg(&ends[node * N_REL - 1]) : 0;
    float acc = 0.0f;

#pragma unroll
    for (int r = 0; r < N_REL; ++r) {
        int end = end_r[r];
        int len = end - prev;
        if (len > 0) {
            float seg = 0.0f;
            int p = prev;
            for (; p + 1 < end; p += 2) {
                int s0 = csr[p], s1 = csr[p + 1];
                seg += b2f(xW16[((s0 << 3) + r) * HID_CH + c]);
                seg += b2f(xW16[((s1 << 3) + r) * HID_CH + c]);
            }
            if (p < end) {
                int s0 = csr[p];
                seg += b2f(xW16[((s0 << 3) + r) * HID_CH + c]);
            }
            acc += seg * (1.0f / (float)len);
            prev = end;
        }
    }

    const float4* xs = (const float4*)(x + ((long)node << 4));
    float4 v0 = xs[0], v1 = xs[1], v2 = xs[2], v3 = xs[3];
    const float* wr = root1 + c;
    acc += b1[c];
    acc += v0.x * wr[0]   + v0.y * wr[32]  + v0.z * wr[64]  + v0.w * wr[96];
    acc += v1.x * wr[128] + v1.y * wr[160] + v1.z * wr[192] + v1.w * wr[224];
    acc += v2.x * wr[256] + v2.y * wr[288] + v2.z * wr[320] + v2.w * wr[352];
    acc += v3.x * wr[384] + v3.y * wr[416] + v3.z * wr[448] + v3.w * wr[480];
    h[(node << 5) + c] = fmaxf(acc, 0.0f);
}

// ---------------------------------------------------------------------------
// l1 fallback (no room for xW16): direct per-edge dot
// ---------------------------------------------------------------------------
__global__ __launch_bounds__(256) void l1_fb_kernel(const float* __restrict__ x,
                                                    const int* __restrict__ csr,
                                                    const int* __restrict__ ends,
                                                    const float* __restrict__ W1,
                                                    const float* __restrict__ root1,
                                                    const float* __restrict__ b1,
                                                    float* __restrict__ h, int N) {
    int gid  = blockIdx.x * 256 + threadIdx.x;
    int node = gid >> 5;
    int c    = gid & 31;
    if (node >= N) return;

    int4 e0 = ((const int4*)ends)[node * 2];
    int4 e1 = ((const int4*)ends)[node * 2 + 1];
    int end_r[N_REL] = {e0.x, e0.y, e0.z, e0.w, e1.x, e1.y, e1.z, e1.w};

    int prev = (node > 0) ? __ldg(&ends[node * N_REL - 1]) : 0;
    float acc = 0.0f;

#pragma unroll
    for (int r = 0; r < N_REL; ++r) {
        int end = end_r[r];
        int len = end - prev;
        if (len > 0) {
            const float* wp = W1 + (r * IN_CH) * HID_CH + c;
            float w[IN_CH];
#pragma unroll
            for (int f = 0; f < IN_CH; ++f) w[f] = wp[f * HID_CH];
            float seg = 0.0f;
            for (int p = prev; p < end; ++p) {
                int s = csr[p];
                const float4* xs = (const float4*)(x + ((long)s << 4));
                float4 v0 = xs[0], v1 = xs[1], v2 = xs[2], v3 = xs[3];
                float a;
                a  = v0.x * w[0]  + v0.y * w[1]  + v0.z * w[2]  + v0.w * w[3];
                a += v1.x * w[4]  + v1.y * w[5]  + v1.z * w[6]  + v1.w * w[7];
                a += v2.x * w[8]  + v2.y * w[9]  + v2.z * w[10] + v2.w * w[11];
                a += v3.x * w[12] + v3.y * w[13] + v3.z * w[14] + v3.w * w[15];
                seg += a;
            }
            acc += seg * (1.0f / (float)len);
            prev = end;
        }
    }

    const float4* xs = (const float4*)(x + ((long)node << 4));
    float4 v0 = xs[0], v1 = xs[1], v2 = xs[2], v3 = xs[3];
    const float* wr = root1 + c;
    acc += b1[c];
    acc += v0.x * wr[0]   + v0.y * wr[32]  + v0.z * wr[64]  + v0.w * wr[96];
    acc += v1.x * wr[128] + v1.y * wr[160] + v1.z * wr[192] + v1.w * wr[224];
    acc += v2.x * wr[256] + v2.y * wr[288] + v2.z * wr[320] + v2.w * wr[352];
    acc += v3.x * wr[384] + v3.y * wr[416] + v3.z * wr[448] + v3.w * wr[480];
    h[(node << 5) + c] = fmaxf(acc, 0.0f);
}

// ---------------------------------------------------------------------------
// hw: hW[n][r][o] = h[n] @ W2[r][:,o];  hroot[n][o] = h[n]@root2[:,o] + b2[o]
// ---------------------------------------------------------------------------
__global__ __launch_bounds__(256) void hw_kernel(const float* __restrict__ h,
                                                 const float* __restrict__ W2,
                                                 const float* __restrict__ root2,
                                                 const float* __restrict__ b2,
                                                 float* __restrict__ hW,
                                                 float* __restrict__ hroot, int N) {
    int gid = blockIdx.x * 256 + threadIdx.x;
    if (gid >= N * 9) return;
    int n = gid / 9;
    int j = gid - n * 9;

    const float* hn = h + ((long)n << 5);
    const float* wp = (j < 8) ? (W2 + j * (HID_CH * OUT_CH)) : root2;

    float o0 = 0.0f, o1 = 0.0f;
#pragma unroll
    for (int f = 0; f < HID_CH; ++f) {
        float hf = hn[f];
        o0 += hf * wp[f * 2 + 0];
        o1 += hf * wp[f * 2 + 1];
    }
    if (j < 8) {
        *(float2*)(hW + ((long)n << 4) + (j << 1)) = make_float2(o0, o1);
    } else {
        *(float2*)(hroot + ((long)n << 1)) = make_float2(o0 + b2[0], o1 + b2[1]);
    }
}

// ---------------------------------------------------------------------------
// l2 finish: 8 lanes per node, lane = relation
// ---------------------------------------------------------------------------
__global__ __launch_bounds__(256) void l2_finish_kernel(const int* __restrict__ csr,
                                                        const int* __restrict__ ends,
                                                        const float* __restrict__ hW,
                                                        const float* __restrict__ hroot,
                                                        float* __restrict__ out, int N) {
    int gid  = blockIdx.x * 256 + threadIdx.x;
    int node = gid >> 3;
    int r    = gid & 7;
    if (node >= N) return;

    int idx  = node * N_REL + r;
    int prev = (idx > 0) ? ends[idx - 1] : 0;
    int end  = ends[idx];

    float o0 = 0.0f, o1 = 0.0f;
    if (end > prev) {
        float s0 = 0.0f, s1 = 0.0f;
        int p = prev;
        for (; p + 1 < end; p += 2) {
            int a = csr[p], b = csr[p + 1];
            float2 va = *(const float2*)(hW + ((long)a << 4) + (r << 1));
            float2 vb = *(const float2*)(hW + ((long)b << 4) + (r << 1));
            s0 += va.x + vb.x; s1 += va.y + vb.y;
        }
        if (p < end) {
            int a = csr[p];
            float2 va = *(const float2*)(hW + ((long)a << 4) + (r << 1));
            s0 += va.x; s1 += va.y;
        }
        float inv = 1.0f / (float)(end - prev);
        o0 = s0 * inv; o1 = s1 * inv;
    }

#pragma unroll
    for (int m = 1; m < 8; m <<= 1) {
        o0 += __shfl_xor(o0, m, 64);
        o1 += __shfl_xor(o1, m, 64);
    }

    if (r == 0) {
        float2 rt = *(const float2*)(hroot + ((long)node << 1));
        o0 += rt.x; o1 += rt.y;
        float mx = fmaxf(o0, o1);
        float l  = mx + logf(__expf(o0 - mx) + __expf(o1 - mx));
        *(float2*)(out + ((long)node << 1)) = make_float2(o0 - l, o1 - l);
    }
}

// ---------------------------------------------------------------------------
extern "C" void kernel_launch(void* const* d_in, const int* in_sizes, int n_in,
                              void* d_out, int out_size, void* d_ws, size_t ws_size,
                              hipStream_t stream) {
    const float* x     = (const float*)d_in[0];
    const int*   eidx  = (const int*)d_in[1];
    const int*   etype = (const int*)d_in[2];
    const float* W1    = (const float*)d_in[3];
    const float* root1 = (const float*)d_in[4];
    const float* b1    = (const float*)d_in[5];
    const float* W2    = (const float*)d_in[6];
    const float* root2 = (const float*)d_in[7];
    const float* b2    = (const float*)d_in[8];
    float* out = (float*)d_out;

    const int N = in_sizes[0] / IN_CH;
    const int E = in_sizes[2];
    const int M = N * N_REL;
    const int nbuck = (N + BNODES - 1) / BNODES;
    const int* src = eidx;
    const int* dst = eidx + E;

    char* wp = (char*)d_ws;
    auto take = [&](size_t bytes) {
        char* p = wp;
        wp += (bytes + 63) & ~(size_t)63;
        return p;
    };
    int*   bbase  = (int*)take((size_t)(nbuck + 1) * sizeof(int));
    int*   ends   = (int*)take((size_t)M * sizeof(int));
    int*   csr    = (int*)take((size_t)E * sizeof(int));
    float* h      = (float*)take((size_t)N * HID_CH * sizeof(float));
    float* hW     = (float*)take((size_t)N * 16 * sizeof(float));
    float* hroot  = (float*)take((size_t)N * 2 * sizeof(float));
    unsigned short* xW16 = (unsigned short*)take((size_t)N * N_REL * HID_CH * sizeof(unsigned short));
    bool use_xw = ((size_t)(wp - (char*)d_ws) <= ws_size);
    int* be = (int*)h;   // alias: be consumed by bucket_build before h is written

    hipMemsetAsync(bbase, 0, (size_t)(nbuck + 1) * sizeof(int), stream);

    const int B = 256;

    bucket_count_kernel<<<(E + B - 1) / B, B, 0, stream>>>(dst, bbase, E);
    bucket_scan_kernel<<<1, 64, 0, stream>>>(bbase, nbuck);
    bucket_scatter_kernel<<<(E + B - 1) / B, B, 0, stream>>>(src, dst, etype, bbase, be, E);
    bucket_build_kernel<<<nbuck, B, 0, stream>>>(be, bbase, ends, csr, M);

    if (use_xw) {
        xw_kernel<<<(N + XW_TILE - 1) / XW_TILE, B, 0, stream>>>(x, W1, xW16, N);
        l1_gather_kernel<<<(N * 32 + B - 1) / B, B, 0, stream>>>(x, csr, ends, xW16, root1, b1, h, N);
    } else {
        l1_fb_kernel<<<(N * 32 + B - 1) / B, B, 0, stream>>>(x, csr, ends, W1, root1, b1, h, N);
    }

    hw_kernel<<<(N * 9 + B - 1) / B, B, 0, stream>>>(h, W2, root2, b2, hW, hroot, N);
    l2_finish_kernel<<<(N * 8 + B - 1) / B, B, 0, stream>>>(csr, ends, hW, hroot, out, N);
}

// Round 6
// 226.158 us; speedup vs baseline: 2.1331x; 2.1331x over previous
//
#include <hip/hip_runtime.h>
#include <math.h>

#define N_REL  8
#define IN_CH  16
#define HID_CH 32
#define OUT_CH 2

#define BIN_BITS  9
#define BIN_NODES 512                    // nodes per coarse bin
#define KPB       (BIN_NODES * N_REL)    // 4096 (node,rel) keys per bin
#define NCHUNK    192                    // partition chunks (blocks)

// float -> bf16 round-to-nearest-even
static __device__ __forceinline__ unsigned short f2b(float f) {
    unsigned int u = __float_as_uint(f);
    u = (u + 0x7FFFu + ((u >> 16) & 1u)) >> 16;
    return (unsigned short)u;
}
static __device__ __forceinline__ float b2f(unsigned short s) {
    return __uint_as_float(((unsigned int)s) << 16);
}

// ---------------------------------------------------------------------------
// B1a: per-chunk histogram over coarse bins (LDS), H[bin][chunk] (bin-major)
// ---------------------------------------------------------------------------
__global__ __launch_bounds__(256) void part_hist_kernel(const int* __restrict__ dst,
                                                        int* __restrict__ H,
                                                        int E, int nbins, int chunksz) {
    __shared__ int hist[256];
    int chunk = blockIdx.x;
    int e0 = chunk * chunksz;
    int e1 = e0 + chunksz; if (e1 > E) e1 = E;

    for (int i = threadIdx.x; i < nbins; i += 256) hist[i] = 0;
    __syncthreads();
    for (int e = e0 + threadIdx.x; e < e1; e += 256)
        atomicAdd(&hist[dst[e] >> BIN_BITS], 1);
    __syncthreads();
    for (int i = threadIdx.x; i < nbins; i += 256)
        H[i * NCHUNK + chunk] = hist[i];
}

// ---------------------------------------------------------------------------
// scan_a/b/c: exclusive scan of H[0..M2) in place
// ---------------------------------------------------------------------------
__global__ __launch_bounds__(1024) void scan_a_kernel(int* __restrict__ ptr,
                                                      int* __restrict__ blksum, int M) {
    int i = blockIdx.x * 1024 + threadIdx.x;
    int val = (i < M) ? ptr[i] : 0;
    int lane = threadIdx.x & 63;
    int wid  = threadIdx.x >> 6;

    int v = val;
#pragma unroll
    for (int off = 1; off < 64; off <<= 1) {
        int u = __shfl_up(v, off, 64);
        if (lane >= off) v += u;
    }

    __shared__ int wsum[16];
    if (lane == 63) wsum[wid] = v;
    __syncthreads();

    if (wid == 0) {
        int worig = (lane < 16) ? wsum[lane] : 0;
        int wv = worig;
#pragma unroll
        for (int off = 1; off < 16; off <<= 1) {
            int u = __shfl_up(wv, off, 64);
            if (lane >= off) wv += u;
        }
        if (lane < 16) wsum[lane] = wv - worig;
        if (lane == 15) blksum[blockIdx.x] = wv;
    }
    __syncthreads();

    if (i < M) ptr[i] = (v - val) + wsum[wid];
}

__global__ void scan_b_kernel(int* __restrict__ blksum, int nb) {
    int lane = threadIdx.x & 63;
    int run = 0;
    for (int base = 0; base < nb; base += 64) {
        int i = base + lane;
        int val = (i < nb) ? blksum[i] : 0;
        int v = val;
#pragma unroll
        for (int off = 1; off < 64; off <<= 1) {
            int u = __shfl_up(v, off, 64);
            if (lane >= off) v += u;
        }
        if (i < nb) blksum[i] = run + (v - val);
        run += __shfl(v, 63, 64);
    }
}

__global__ __launch_bounds__(1024) void scan_c_kernel(int* __restrict__ ptr,
                                                      const int* __restrict__ blksum, int M) {
    int i = blockIdx.x * 1024 + threadIdx.x;
    if (i < M) ptr[i] += blksum[blockIdx.x];
}

// ---------------------------------------------------------------------------
// B1b: partition — chunk-block writes packed records to per-(bin,chunk) runs.
// pack: (localdst<<20) | (rel<<17) | src   (src < 2^17, localdst < 512)
// ---------------------------------------------------------------------------
__global__ __launch_bounds__(256) void part_scatter_kernel(const int* __restrict__ src,
                                                           const int* __restrict__ dst,
                                                           const int* __restrict__ rel,
                                                           const int* __restrict__ Hs,
                                                           int* __restrict__ be,
                                                           int E, int nbins, int chunksz) {
    __shared__ int base[256];
    __shared__ int fil[256];
    int chunk = blockIdx.x;
    int e0 = chunk * chunksz;
    int e1 = e0 + chunksz; if (e1 > E) e1 = E;

    for (int i = threadIdx.x; i < nbins; i += 256) {
        base[i] = Hs[i * NCHUNK + chunk];
        fil[i]  = 0;
    }
    __syncthreads();

    for (int e = e0 + threadIdx.x; e < e1; e += 256) {
        int d = dst[e];
        int b = d >> BIN_BITS;
        int slot = base[b] + atomicAdd(&fil[b], 1);
        be[slot] = ((d & (BIN_NODES - 1)) << 20) | (rel[e] << 17) | src[e];
    }
}

// ---------------------------------------------------------------------------
// B2: one block per bin — LDS counting sort over 4096 keys -> ends[] + csr[].
// All global writes by this block land in the bin's private contiguous range.
// ---------------------------------------------------------------------------
__global__ __launch_bounds__(256) void bin_build_kernel(const int* __restrict__ be,
                                                        const int* __restrict__ Hs,
                                                        int* __restrict__ ends,
                                                        int* __restrict__ csr,
                                                        int E, int nbins) {
    int b  = blockIdx.x;
    int s0 = Hs[b * NCHUNK];
    int s1 = (b + 1 < nbins) ? Hs[(b + 1) * NCHUNK] : E;
    int t  = threadIdx.x;

    __shared__ int cnt[KPB];
    __shared__ int off[KPB];   // exclusive start per key (bin-local)
    __shared__ int fil[KPB];
    __shared__ int ws[4];

    for (int i = t; i < KPB; i += 256) { cnt[i] = 0; fil[i] = 0; }
    __syncthreads();

    for (int p = s0 + t; p < s1; p += 256)
        atomicAdd(&cnt[be[p] >> 17], 1);          // key = (localdst<<3)|rel
    __syncthreads();

    // block scan: each thread serial-scans 16 keys, then scan the 256 partials
    int kbase = t * 16;
    int loc[16];
    int sum = 0;
#pragma unroll
    for (int i = 0; i < 16; ++i) { loc[i] = sum; sum += cnt[kbase + i]; }

    int lane = t & 63, wid = t >> 6;
    int v = sum;
#pragma unroll
    for (int o = 1; o < 64; o <<= 1) {
        int u = __shfl_up(v, o, 64);
        if (lane >= o) v += u;
    }
    if (lane == 63) ws[wid] = v;
    __syncthreads();
    int woff = 0;
    for (int i = 0; i < wid; ++i) woff += ws[i];
    int excl = woff + (v - sum);
#pragma unroll
    for (int i = 0; i < 16; ++i) off[kbase + i] = excl + loc[i];
    __syncthreads();

    // inclusive global segment ends (coalesced, streaming)
    for (int i = t; i < KPB; i += 256)
        ends[b * KPB + i] = s0 + off[i] + cnt[i];

    // scatter into csr (bin-private ~32KB range; single block owns the lines)
    for (int p = s0 + t; p < s1; p += 256) {
        int pk = be[p];
        int k  = pk >> 17;
        int slot = s0 + off[k] + atomicAdd(&fil[k], 1);
        csr[slot] = pk & 0x1FFFF;
    }
}

// ---------------------------------------------------------------------------
// xw: xW16[n][r][c] = bf16( x[n] @ W1[r][:,c] )
// ---------------------------------------------------------------------------
#define XW_TILE 64
__global__ __launch_bounds__(256) void xw_kernel(const float* __restrict__ x,
                                                 const float* __restrict__ W1,
                                                 unsigned short* __restrict__ xW16, int N) {
    __shared__ float sx[XW_TILE * IN_CH];   // 4 KB
    int t = threadIdx.x;
    int node0 = blockIdx.x * XW_TILE;

    {
        int i4 = node0 * 4 + t;
        float4 v = make_float4(0.f, 0.f, 0.f, 0.f);
        if (i4 < N * 4) v = ((const float4*)x)[i4];
        ((float4*)sx)[t] = v;
    }
    __syncthreads();

    int r = t >> 5, c = t & 31;
    float w[IN_CH];
#pragma unroll
    for (int f = 0; f < IN_CH; ++f)
        w[f] = W1[(r * IN_CH + f) * HID_CH + c];

    int lim = N - node0; if (lim > XW_TILE) lim = XW_TILE;
    for (int ni = 0; ni < lim; ++ni) {
        const float4* xs = (const float4*)(sx + ni * IN_CH);
        float4 v0 = xs[0], v1 = xs[1], v2 = xs[2], v3 = xs[3];
        float a;
        a  = v0.x * w[0]  + v0.y * w[1]  + v0.z * w[2]  + v0.w * w[3];
        a += v1.x * w[4]  + v1.y * w[5]  + v1.z * w[6]  + v1.w * w[7];
        a += v2.x * w[8]  + v2.y * w[9]  + v2.z * w[10] + v2.w * w[11];
        a += v3.x * w[12] + v3.y * w[13] + v3.z * w[14] + v3.w * w[15];
        xW16[(node0 + ni) * (N_REL * HID_CH) + t] = f2b(a);
    }
}

// ---------------------------------------------------------------------------
// l1 gather: half-wave per node, lane = hidden channel c.
// ---------------------------------------------------------------------------
__global__ __launch_bounds__(256) void l1_gather_kernel(const float* __restrict__ x,
                                                        const int* __restrict__ csr,
                                                        const int* __restrict__ ends,
                                                        const unsigned short* __restrict__ xW16,
                                                        const float* __restrict__ root1,
                                                        const float* __restrict__ b1,
                                                        float* __restrict__ h, int N) {
    int gid  = blockIdx.x * 256 + threadIdx.x;
    int node = gid >> 5;
    int c    = gid & 31;
    if (node >= N) return;

    int4 e0 = ((const int4*)ends)[node * 2];
    int4 e1 = ((const int4*)ends)[node * 2 + 1];
    int end_r[N_REL] = {e0.x, e0.y, e0.z, e0.w, e1.x, e1.y, e1.z, e1.w};

    int prev = (node > 0) ? __ldg(&ends[node * N_REL - 1]) : 0;
    float acc = 0.0f;

#pragma unroll
    for (int r = 0; r < N_REL; ++r) {
        int end = end_r[r];
        int len = end - prev;
        if (len > 0) {
            float seg = 0.0f;
            int p = prev;
            for (; p + 1 < end; p += 2) {
                int s0 = csr[p], s1 = csr[p + 1];
                seg += b2f(xW16[((s0 << 3) + r) * HID_CH + c]);
                seg += b2f(xW16[((s1 << 3) + r) * HID_CH + c]);
            }
            if (p < end) {
                int s0 = csr[p];
                seg += b2f(xW16[((s0 << 3) + r) * HID_CH + c]);
            }
            acc += seg * (1.0f / (float)len);
            prev = end;
        }
    }

    const float4* xs = (const float4*)(x + ((long)node << 4));
    float4 v0 = xs[0], v1 = xs[1], v2 = xs[2], v3 = xs[3];
    const float* wr = root1 + c;
    acc += b1[c];
    acc += v0.x * wr[0]   + v0.y * wr[32]  + v0.z * wr[64]  + v0.w * wr[96];
    acc += v1.x * wr[128] + v1.y * wr[160] + v1.z * wr[192] + v1.w * wr[224];
    acc += v2.x * wr[256] + v2.y * wr[288] + v2.z * wr[320] + v2.w * wr[352];
    acc += v3.x * wr[384] + v3.y * wr[416] + v3.z * wr[448] + v3.w * wr[480];
    h[(node << 5) + c] = fmaxf(acc, 0.0f);
}

// ---------------------------------------------------------------------------
// l1 fallback (no room for xW16): direct per-edge dot
// ---------------------------------------------------------------------------
__global__ __launch_bounds__(256) void l1_fb_kernel(const float* __restrict__ x,
                                                    const int* __restrict__ csr,
                                                    const int* __restrict__ ends,
                                                    const float* __restrict__ W1,
                                                    const float* __restrict__ root1,
                                                    const float* __restrict__ b1,
                                                    float* __restrict__ h, int N) {
    int gid  = blockIdx.x * 256 + threadIdx.x;
    int node = gid >> 5;
    int c    = gid & 31;
    if (node >= N) return;

    int4 e0 = ((const int4*)ends)[node * 2];
    int4 e1 = ((const int4*)ends)[node * 2 + 1];
    int end_r[N_REL] = {e0.x, e0.y, e0.z, e0.w, e1.x, e1.y, e1.z, e1.w};

    int prev = (node > 0) ? __ldg(&ends[node * N_REL - 1]) : 0;
    float acc = 0.0f;

#pragma unroll
    for (int r = 0; r < N_REL; ++r) {
        int end = end_r[r];
        int len = end - prev;
        if (len > 0) {
            const float* wp = W1 + (r * IN_CH) * HID_CH + c;
            float w[IN_CH];
#pragma unroll
            for (int f = 0; f < IN_CH; ++f) w[f] = wp[f * HID_CH];
            float seg = 0.0f;
            for (int p = prev; p < end; ++p) {
                int s = csr[p];
                const float4* xs = (const float4*)(x + ((long)s << 4));
                float4 v0 = xs[0], v1 = xs[1], v2 = xs[2], v3 = xs[3];
                float a;
                a  = v0.x * w[0]  + v0.y * w[1]  + v0.z * w[2]  + v0.w * w[3];
                a += v1.x * w[4]  + v1.y * w[5]  + v1.z * w[6]  + v1.w * w[7];
                a += v2.x * w[8]  + v2.y * w[9]  + v2.z * w[10] + v2.w * w[11];
                a += v3.x * w[12] + v3.y * w[13] + v3.z * w[14] + v3.w * w[15];
                seg += a;
            }
            acc += seg * (1.0f / (float)len);
            prev = end;
        }
    }

    const float4* xs = (const float4*)(x + ((long)node << 4));
    float4 v0 = xs[0], v1 = xs[1], v2 = xs[2], v3 = xs[3];
    const float* wr = root1 + c;
    acc += b1[c];
    acc += v0.x * wr[0]   + v0.y * wr[32]  + v0.z * wr[64]  + v0.w * wr[96];
    acc += v1.x * wr[128] + v1.y * wr[160] + v1.z * wr[192] + v1.w * wr[224];
    acc += v2.x * wr[256] + v2.y * wr[288] + v2.z * wr[320] + v2.w * wr[352];
    acc += v3.x * wr[384] + v3.y * wr[416] + v3.z * wr[448] + v3.w * wr[480];
    h[(node << 5) + c] = fmaxf(acc, 0.0f);
}

// ---------------------------------------------------------------------------
// hw: hW[n][r][o] = h[n] @ W2[r][:,o];  hroot[n][o] = h[n]@root2[:,o] + b2[o]
// ---------------------------------------------------------------------------
__global__ __launch_bounds__(256) void hw_kernel(const float* __restrict__ h,
                                                 const float* __restrict__ W2,
                                                 const float* __restrict__ root2,
                                                 const float* __restrict__ b2,
                                                 float* __restrict__ hW,
                                                 float* __restrict__ hroot, int N) {
    int gid = blockIdx.x * 256 + threadIdx.x;
    if (gid >= N * 9) return;
    int n = gid / 9;
    int j = gid - n * 9;

    const float* hn = h + ((long)n << 5);
    const float* wp = (j < 8) ? (W2 + j * (HID_CH * OUT_CH)) : root2;

    float o0 = 0.0f, o1 = 0.0f;
#pragma unroll
    for (int f = 0; f < HID_CH; ++f) {
        float hf = hn[f];
        o0 += hf * wp[f * 2 + 0];
        o1 += hf * wp[f * 2 + 1];
    }
    if (j < 8) {
        *(float2*)(hW + ((long)n << 4) + (j << 1)) = make_float2(o0, o1);
    } else {
        *(float2*)(hroot + ((long)n << 1)) = make_float2(o0 + b2[0], o1 + b2[1]);
    }
}

// ---------------------------------------------------------------------------
// l2 finish: 8 lanes per node, lane = relation
// ---------------------------------------------------------------------------
__global__ __launch_bounds__(256) void l2_finish_kernel(const int* __restrict__ csr,
                                                        const int* __restrict__ ends,
                                                        const float* __restrict__ hW,
                                                        const float* __restrict__ hroot,
                                                        float* __restrict__ out, int N) {
    int gid  = blockIdx.x * 256 + threadIdx.x;
    int node = gid >> 3;
    int r    = gid & 7;
    if (node >= N) return;

    int idx  = node * N_REL + r;
    int prev = (idx > 0) ? ends[idx - 1] : 0;
    int end  = ends[idx];

    float o0 = 0.0f, o1 = 0.0f;
    if (end > prev) {
        float s0 = 0.0f, s1 = 0.0f;
        int p = prev;
        for (; p + 1 < end; p += 2) {
            int a = csr[p], b = csr[p + 1];
            float2 va = *(const float2*)(hW + ((long)a << 4) + (r << 1));
            float2 vb = *(const float2*)(hW + ((long)b << 4) + (r << 1));
            s0 += va.x + vb.x; s1 += va.y + vb.y;
        }
        if (p < end) {
            int a = csr[p];
            float2 va = *(const float2*)(hW + ((long)a << 4) + (r << 1));
            s0 += va.x; s1 += va.y;
        }
        float inv = 1.0f / (float)(end - prev);
        o0 = s0 * inv; o1 = s1 * inv;
    }

#pragma unroll
    for (int m = 1; m < 8; m <<= 1) {
        o0 += __shfl_xor(o0, m, 64);
        o1 += __shfl_xor(o1, m, 64);
    }

    if (r == 0) {
        float2 rt = *(const float2*)(hroot + ((long)node << 1));
        o0 += rt.x; o1 += rt.y;
        float mx = fmaxf(o0, o1);
        float l  = mx + logf(__expf(o0 - mx) + __expf(o1 - mx));
        *(float2*)(out + ((long)node << 1)) = make_float2(o0 - l, o1 - l);
    }
}

// ---------------------------------------------------------------------------
extern "C" void kernel_launch(void* const* d_in, const int* in_sizes, int n_in,
                              void* d_out, int out_size, void* d_ws, size_t ws_size,
                              hipStream_t stream) {
    const float* x     = (const float*)d_in[0];
    const int*   eidx  = (const int*)d_in[1];
    const int*   etype = (const int*)d_in[2];
    const float* W1    = (const float*)d_in[3];
    const float* root1 = (const float*)d_in[4];
    const float* b1    = (const float*)d_in[5];
    const float* W2    = (const float*)d_in[6];
    const float* root2 = (const float*)d_in[7];
    const float* b2    = (const float*)d_in[8];
    float* out = (float*)d_out;

    const int N = in_sizes[0] / IN_CH;
    const int E = in_sizes[2];
    const int nbins   = (N + BIN_NODES - 1) >> BIN_BITS;   // 196 for N=100k
    const int chunksz = (E + NCHUNK - 1) / NCHUNK;
    const int M2      = nbins * NCHUNK;
    const int* src = eidx;
    const int* dst = eidx + E;

    char* wp = (char*)d_ws;
    auto take = [&](size_t bytes) {
        char* p = wp;
        wp += (bytes + 63) & ~(size_t)63;
        return p;
    };
    int*   H      = (int*)take((size_t)M2 * sizeof(int));
    int*   blksum = (int*)take(4096 * sizeof(int));
    int*   ends   = (int*)take((size_t)nbins * KPB * sizeof(int));
    int*   csr    = (int*)take((size_t)E * sizeof(int));
    float* h      = (float*)take((size_t)N * HID_CH * sizeof(float));
    float* hW     = (float*)take((size_t)N * 16 * sizeof(float));
    float* hroot  = (float*)take((size_t)N * 2 * sizeof(float));
    unsigned short* xW16 = (unsigned short*)take((size_t)N * N_REL * HID_CH * sizeof(unsigned short));
    bool use_xw = ((size_t)(wp - (char*)d_ws) <= ws_size);
    int* be = (int*)h;   // alias: be is dead before h's first write (l1 runs after bin_build)

    const int B = 256;
    const int nb = (M2 + 1023) / 1024;

    part_hist_kernel<<<NCHUNK, B, 0, stream>>>(dst, H, E, nbins, chunksz);
    scan_a_kernel<<<nb, 1024, 0, stream>>>(H, blksum, M2);
    scan_b_kernel<<<1, 64, 0, stream>>>(blksum, nb);
    scan_c_kernel<<<nb, 1024, 0, stream>>>(H, blksum, M2);
    part_scatter_kernel<<<NCHUNK, B, 0, stream>>>(src, dst, etype, H, be, E, nbins, chunksz);
    bin_build_kernel<<<nbins, B, 0, stream>>>(be, H, ends, csr, E, nbins);

    if (use_xw) {
        xw_kernel<<<(N + XW_TILE - 1) / XW_TILE, B, 0, stream>>>(x, W1, xW16, N);
        l1_gather_kernel<<<(N * 32 + B - 1) / B, B, 0, stream>>>(x, csr, ends, xW16, root1, b1, h, N);
    } else {
        l1_fb_kernel<<<(N * 32 + B - 1) / B, B, 0, stream>>>(x, csr, ends, W1, root1, b1, h, N);
    }

    hw_kernel<<<(N * 9 + B - 1) / B, B, 0, stream>>>(h, W2, root2, b2, hW, hroot, N);
    l2_finish_kernel<<<(N * 8 + B - 1) / B, B, 0, stream>>>(csr, ends, hW, hroot, out, N);
}